// Round 5
// baseline (574.561 us; speedup 1.0000x reference)
//
#include <hip/hip_runtime.h>
#include <hip/hip_bf16.h>

// Problem constants (B=2, S=2048, D=1536, H=12, hd=128)
#define S_LEN   2048
#define DMODEL  1536
#define NBATCH  2
#define NHEADS  12
#define MROWS   (NBATCH * S_LEN)        // 4096
#define NCHUNK  64                      // scan chunks per sequence (32 rows each)
#define CHUNK   32

typedef unsigned short u16;
typedef __attribute__((ext_vector_type(8))) short bf16x8;   // 8 bf16 = 4 VGPRs
typedef __attribute__((ext_vector_type(4))) float f32x4;    // native vec4 (MFMA acc + NT stores)

// round-to-nearest-even fp32 -> bf16
__device__ __forceinline__ u16 f2bf(float x) {
  unsigned u = __float_as_uint(x);
  u += 0x7fffu + ((u >> 16) & 1u);
  return (u16)(u >> 16);
}
__device__ __forceinline__ float bf2f(u16 x) {
  return __uint_as_float(((unsigned)x) << 16);
}

// ---------------------------------------------------------------- fused cvt fp32->bf16 (3 tensors)
#define N4_HID  1572864     // 2*2048*1536/4
#define N4_W    589824      // 1536*1536/4
__global__ void cvt_all(const float4* __restrict__ h, const float4* __restrict__ wf,
                        const float4* __restrict__ wp, ushort4* __restrict__ ho,
                        ushort4* __restrict__ wfo, ushort4* __restrict__ wpo) {
  int t = blockIdx.x * blockDim.x + threadIdx.x;   // N4_HID + 2*N4_W = 2752512
  const float4* src;
  ushort4* dst;
  int idx;
  if (t < N4_HID)            { src = h;  dst = ho;  idx = t; }
  else if (t < N4_HID + N4_W){ src = wf; dst = wfo; idx = t - N4_HID; }
  else                       { src = wp; dst = wpo; idx = t - N4_HID - N4_W; }
  float4 f = src[idx];
  ushort4 o;
  o.x = f2bf(f.x); o.y = f2bf(f.y); o.z = f2bf(f.z); o.w = f2bf(f.w);
  dst[idx] = o;
}

// ---------------------------------------------------------------- bf16 GEMM  C = A @ B^T + bias
// m97 structure: 128x128 tile, BK=32, 4 waves (2x2 of 64x64), 16x16x32 MFMA,
// global_load_lds width=16 staging. Output type templated (fp32 or bf16).
// WITH_CSUM additionally emits per-column sums over each 32-row group of the
// tile (the scan chunk sums) straight from the accumulators — no extra reads.
__device__ __forceinline__ void gld_lds16(u16* lds, const u16* g) {
  __builtin_amdgcn_global_load_lds(
      (const __attribute__((address_space(1))) unsigned int*)g,
      (__attribute__((address_space(3))) unsigned int*)lds, 16, 0, 0);
}

template <bool WITH_CSUM, typename CT>
__global__ __launch_bounds__(256)
void gemm_bt_bias(const u16* __restrict__ A, const u16* __restrict__ B,
                  const float* __restrict__ bias, CT* __restrict__ C,
                  float* __restrict__ cs, int Ndim, int Kdim) {
  __shared__ __align__(16) u16 As[128 * 32];   // row-major, row stride 32 bf16 (64 B)
  __shared__ __align__(16) u16 Bs[128 * 32];
  __shared__ float colpart[4][128];            // 32-row-group column sums

  const int tid  = threadIdx.x;
  const int wave = tid >> 6;
  const int lane = tid & 63;
  const int l15  = lane & 15;
  const int quad = lane >> 4;
  const int bm = blockIdx.y * 128;
  const int bn = blockIdx.x * 128;
  const int wm = (wave >> 1) * 64;
  const int wn = (wave & 1) * 64;

  f32x4 acc[4][4] = {};

  const int srow = wave * 32 + (lane >> 2);
  const int skk  = (lane & 3) * 8;
  const u16* gA = A + (size_t)(bm + srow) * Kdim + skk;
  const u16* gB = B + (size_t)(bn + srow) * Kdim + skk;
  u16* lA = &As[(wave * 32) * 32];
  u16* lB = &Bs[(wave * 32) * 32];
  const size_t rstep16 = (size_t)16 * Kdim;

  for (int k0 = 0; k0 < Kdim; k0 += 32) {
    gld_lds16(lA,           gA + k0);
    gld_lds16(lA + 16 * 32, gA + k0 + rstep16);
    gld_lds16(lB,           gB + k0);
    gld_lds16(lB + 16 * 32, gB + k0 + rstep16);
    __syncthreads();

    bf16x8 af[4], bfr[4];
#pragma unroll
    for (int i = 0; i < 4; ++i)
      af[i] = *(const bf16x8*)&As[(wm + i * 16 + l15) * 32 + quad * 8];
#pragma unroll
    for (int j = 0; j < 4; ++j)
      bfr[j] = *(const bf16x8*)&Bs[(wn + j * 16 + l15) * 32 + quad * 8];
#pragma unroll
    for (int i = 0; i < 4; ++i)
#pragma unroll
      for (int j = 0; j < 4; ++j)
        acc[i][j] = __builtin_amdgcn_mfma_f32_16x16x32_bf16(af[i], bfr[j], acc[i][j], 0, 0, 0);
    __syncthreads();
  }

  // epilogue: C/D layout col = lane&15, row = quad*4 + reg   [verified m89/m91]
  const int r0 = quad * 4;
#pragma unroll
  for (int j = 0; j < 4; ++j) {
    const int col = bn + wn + j * 16 + l15;
    const float bj = bias[col];
    float sA = 0.f, sB = 0.f;     // rows [wm, wm+32) and [wm+32, wm+64)
#pragma unroll
    for (int i = 0; i < 4; ++i) {
      const int row = bm + wm + i * 16 + r0;
#pragma unroll
      for (int r = 0; r < 4; ++r) {
        float cv = acc[i][j][r] + bj;
        if constexpr (sizeof(CT) == 2)
          C[(size_t)(row + r) * Ndim + col] = (CT)f2bf(cv);
        else
          C[(size_t)(row + r) * Ndim + col] = (CT)cv;
        if (WITH_CSUM) { if (i < 2) sA += cv; else sB += cv; }
      }
    }
    if (WITH_CSUM) {
      sA += __shfl_xor(sA, 16); sA += __shfl_xor(sA, 32);
      sB += __shfl_xor(sB, 16); sB += __shfl_xor(sB, 32);
      if (quad == 0) {
        colpart[(wm >> 5) | 0][wn + j * 16 + l15] = sA;
        colpart[(wm >> 5) | 1][wn + j * 16 + l15] = sB;
      }
    }
  }
  if (WITH_CSUM) {
    __syncthreads();
    if (tid < 128) {
      const int b  = bm >> 11;               // 2048 rows per batch
      const int c0 = (bm & 2047) >> 5;       // first 32-row chunk of this tile
#pragma unroll
      for (int g = 0; g < 4; ++g)
        cs[((size_t)b * NCHUNK + c0 + g) * DMODEL + bn + tid] = colpart[g][tid];
    }
  }
}

// ---------------------------------------------------------------- exclusive chunk prefix
// E[b,c,d] = sum_{cc<c} cs[b,cc,d] = P[c*32 - 1].  One thread per (b,c,d);
// <=63 INDEPENDENT L2-resident loads (no dependent chain), fully coalesced.
__global__ void chunk_prefix(const float* __restrict__ cs, float* __restrict__ E) {
  int t = blockIdx.x * blockDim.x + threadIdx.x;   // NBATCH*NCHUNK*DMODEL = 196608
  int d = t % DMODEL;
  int c = (t / DMODEL) % NCHUNK;
  int b = t / (DMODEL * NCHUNK);
  const float* p = cs + (size_t)b * NCHUNK * DMODEL + d;
  float s = 0.f;
  for (int cc = 0; cc < c; ++cc) s += p[(size_t)cc * DMODEL];   // block-uniform trip
  E[t] = s;
}

// ---------------------------------------------------------------- windowed average (strip=8)
// One thread per (b, 8-row strip, d): 786k threads / 3072 blocks, ~45 bf16
// loads per strip against L3-resident v16. Branches wave-uniform (64
// consecutive d never cross a head boundary).
__global__ void winavg_strip(const u16* __restrict__ v, const float* __restrict__ E,
                             u16* __restrict__ A2) {
  int t = blockIdx.x * blockDim.x + threadIdx.x;   // NBATCH*(S_LEN/8)*DMODEL = 786432
  int d = t % DMODEL;
  int s = (t / DMODEL) & 255;                      // strip index, S_LEN/8 = 256
  int b = t / (DMODEL * 256);
  const int h = d >> 7;
  const int w = (2 << h) - 1;                      // 2^(h+1)-1
  const u16* vb  = v + (size_t)b * S_LEN * DMODEL + d;
  const float* Eb = E + (size_t)b * NCHUNK * DMODEL + d;

  const int i0 = s * 8;
  // lead = P[i0-1]
  float lead = Eb[(size_t)(i0 >> 5) * DMODEL];
  for (int r = i0 & ~31; r < i0; ++r)              // trip in {0,8,16,24}, uniform
    lead += bf2f(vb[(size_t)r * DMODEL]);

  // trail = P[jf-1] where jf = first trail index the strip will consume
  float trail = 0.f;
  if (i0 + 7 >= w) {                               // wave-uniform
    const int jf = max(i0, w) - w;
    if (jf > 0) {
      const int ct = (jf - 1) >> 5;
      trail = Eb[(size_t)ct * DMODEL];
      for (int r = ct * 32; r < jf; ++r)           // trip <=32, uniform
        trail += bf2f(vb[(size_t)r * DMODEL]);
    }
  }

  u16* out = A2 + ((size_t)(b * S_LEN + i0)) * DMODEL + d;
#pragma unroll
  for (int rr = 0; rr < 8; ++rr) {
    const int i = i0 + rr;
    lead += bf2f(vb[(size_t)i * DMODEL]);          // lead = P[i]
    float o;
    if (i < w) {                                   // window not yet full (uniform)
      o = lead / (float)(i + 1);
    } else {
      trail += bf2f(vb[(size_t)(i - w) * DMODEL]); // trail = P[i-w]
      o = (lead - trail) / (float)w;
    }
    out[(size_t)rr * DMODEL] = f2bf(o);
  }
}

// ---------------------------------------------------------------- analytic attn_weights [B,H,S,S]
__global__ void attn_weights_kernel(f32x4* __restrict__ out4) {
  int t = blockIdx.x * blockDim.x + threadIdx.x;   // B*H*S*S/4
  int j0 = (t & 511) << 2;
  int i  = (t >> 9) & (S_LEN - 1);
  int bh = t >> 20;                                // S*S/4 = 2^20
  int h  = bh >= NHEADS ? bh - NHEADS : bh;
  int w  = (2 << h) - 1;
  int len = min(i + 1, w);
  float inv = 1.0f / (float)len;
  int lo = i - w + 1;
  f32x4 r;
  r.x = (j0     <= i && j0     >= lo) ? inv : 0.f;
  r.y = (j0 + 1 <= i && j0 + 1 >= lo) ? inv : 0.f;
  r.z = (j0 + 2 <= i && j0 + 2 >= lo) ? inv : 0.f;
  r.w = (j0 + 3 <= i && j0 + 3 >= lo) ? inv : 0.f;
  __builtin_nontemporal_store(r, &out4[t]);        // 402 MB pure stream — skip L2
}

// ---------------------------------------------------------------- launch
extern "C" void kernel_launch(void* const* d_in, const int* in_sizes, int n_in,
                              void* d_out, int out_size, void* d_ws, size_t ws_size,
                              hipStream_t stream) {
  const float* hidden = (const float*)d_in[0];
  const float* W_fc   = (const float*)d_in[1];
  const float* b_fc   = (const float*)d_in[2];
  const float* W_proj = (const float*)d_in[3];
  const float* b_proj = (const float*)d_in[4];
  float* outp = (float*)d_out;

  // workspace layout (bytes), total 36.2 MB:
  //   0        : A16   (12,582,912)  hidden bf16, later reused as winavg-output bf16
  //   12582912 : Wfc16 ( 4,718,592)
  //   17301504 : Wpj16 ( 4,718,592)
  //   22020096 : v16   (12,582,912)  bf16 v from GEMM1
  //   34603008 : csums (   786,432)  [B, NCHUNK, D] fp32 32-row chunk sums
  //   35389440 : Epre  (   786,432)  [B, NCHUNK, D] fp32 exclusive chunk prefix
  char* ws = (char*)d_ws;
  u16*   A16   = (u16*)(ws);
  u16*   Wfc16 = (u16*)(ws + 12582912);
  u16*   Wpj16 = (u16*)(ws + 17301504);
  u16*   v16   = (u16*)(ws + 22020096);
  float* csums = (float*)(ws + 34603008);
  float* Epre  = (float*)(ws + 35389440);

  // 1) all fp32->bf16 conversions in one launch
  cvt_all<<<10752, 256, 0, stream>>>((const float4*)hidden, (const float4*)W_fc,
                                     (const float4*)W_proj, (ushort4*)A16,
                                     (ushort4*)Wfc16, (ushort4*)Wpj16);

  // 2) GEMM1: v = hidden @ W_fc^T + b_fc -> bf16, fused 32-row chunk column sums
  gemm_bt_bias<true, u16><<<dim3(DMODEL / 128, MROWS / 128), 256, 0, stream>>>(
      A16, Wfc16, b_fc, v16, csums, DMODEL, DMODEL);

  // 3a) exclusive prefix of chunk sums (tiny, parallel)
  chunk_prefix<<<(NBATCH * NCHUNK * DMODEL) / 256, 256, 0, stream>>>(csums, Epre);

  // 3b) windowed average, 8-row strips, fully parallel -> bf16 (reuse A16)
  winavg_strip<<<(NBATCH * (S_LEN / 8) * DMODEL) / 256, 256, 0, stream>>>(v16, Epre, A16);

  // 4) GEMM2: out = winavg @ W_proj^T + b_proj -> d_out[0 : B*S*D] fp32
  gemm_bt_bias<false, float><<<dim3(DMODEL / 128, MROWS / 128), 256, 0, stream>>>(
      A16, Wpj16, b_proj, outp, nullptr, DMODEL, DMODEL);

  // 5) attn_weights -> d_out[B*S*D : ...]
  attn_weights_kernel<<<(NBATCH * NHEADS * S_LEN * S_LEN / 4) / 256, 256, 0, stream>>>(
      (f32x4*)(outp + (size_t)MROWS * DMODEL));
}

// Round 6
// 541.088 us; speedup vs baseline: 1.0619x; 1.0619x over previous
//
#include <hip/hip_runtime.h>
#include <hip/hip_bf16.h>

// Problem constants (B=2, S=2048, D=1536, H=12, hd=128)
#define S_LEN   2048
#define DMODEL  1536
#define NBATCH  2
#define NHEADS  12
#define MROWS   (NBATCH * S_LEN)        // 4096
#define NCHUNK  64                      // scan chunks per sequence (32 rows each)
#define CHUNK   32

#define NGEMM_BLK  384                  // (MROWS/128) * (DMODEL/128) = 32*12
#define AW_BLK     3072                 // attn-weights writer blocks per GEMM launch
#define AW_TOTAL4  25165824u            // B*H*S*S/4 f32x4 elements (402.7 MB)
#define AW_HALF4   12582912u

typedef unsigned short u16;
typedef __attribute__((ext_vector_type(8))) short bf16x8;   // 8 bf16 = 4 VGPRs
typedef __attribute__((ext_vector_type(4))) float f32x4;    // native vec4 (acc + NT stores)

// round-to-nearest-even fp32 -> bf16
__device__ __forceinline__ u16 f2bf(float x) {
  unsigned u = __float_as_uint(x);
  u += 0x7fffu + ((u >> 16) & 1u);
  return (u16)(u >> 16);
}
__device__ __forceinline__ float bf2f(u16 x) {
  return __uint_as_float(((unsigned)x) << 16);
}

// ---------------------------------------------------------------- fused cvt fp32->bf16 (3 tensors)
#define N4_HID  1572864     // 2*2048*1536/4
#define N4_W    589824      // 1536*1536/4
__global__ void cvt_all(const float4* __restrict__ h, const float4* __restrict__ wf,
                        const float4* __restrict__ wp, ushort4* __restrict__ ho,
                        ushort4* __restrict__ wfo, ushort4* __restrict__ wpo) {
  int t = blockIdx.x * blockDim.x + threadIdx.x;   // N4_HID + 2*N4_W = 2752512
  const float4* src;
  ushort4* dst;
  int idx;
  if (t < N4_HID)            { src = h;  dst = ho;  idx = t; }
  else if (t < N4_HID + N4_W){ src = wf; dst = wfo; idx = t - N4_HID; }
  else                       { src = wp; dst = wpo; idx = t - N4_HID - N4_W; }
  float4 f = src[idx];
  ushort4 o;
  o.x = f2bf(f.x); o.y = f2bf(f.y); o.z = f2bf(f.z); o.w = f2bf(f.w);
  dst[idx] = o;
}

// ---------------------------------------------------------------- GEMM + attn-weights hybrid
// 1D grid: blocks [0, NGEMM_BLK) run the m97-structure bf16 GEMM C = A@B^T + bias
// (128x128 tile, BK=32, 4 waves, 16x16x32 MFMA, global_load_lds width=16).
// Blocks [NGEMM_BLK, NGEMM_BLK+AW_BLK) stream analytic attn_weights with
// nontemporal f32x4 stores — pure-VMEM waves that co-schedule with the MFMA
// waves on the same CUs (m114: time = max, not sum), hiding ~200 MB of writes
// per launch under GEMM compute and filling the 384-block grid's idle slots.
__device__ __forceinline__ void gld_lds16(u16* lds, const u16* g) {
  __builtin_amdgcn_global_load_lds(
      (const __attribute__((address_space(1))) unsigned int*)g,
      (__attribute__((address_space(3))) unsigned int*)lds, 16, 0, 0);
}

template <bool WITH_CSUM, typename CT>
__global__ __launch_bounds__(256)
void gemm_aw(const u16* __restrict__ A, const u16* __restrict__ B,
             const float* __restrict__ bias, CT* __restrict__ C,
             float* __restrict__ cs, f32x4* __restrict__ aw,
             unsigned aw0, unsigned awcnt, int Ndim, int Kdim) {
  // ---- attn-weights path (no LDS use, returns before any barrier) ----
  if ((int)blockIdx.x >= NGEMM_BLK) {
    const unsigned stride = (gridDim.x - NGEMM_BLK) * 256u;
    const unsigned end = aw0 + awcnt;
    unsigned t = aw0 + (blockIdx.x - NGEMM_BLK) * 256u + threadIdx.x;
    for (; t < end; t += stride) {
      int j0 = (int)(t & 511u) << 2;
      int i  = (int)(t >> 9) & (S_LEN - 1);
      int bh = (int)(t >> 20);                     // S*S/4 = 2^20 per (b,h)
      int h  = bh >= NHEADS ? bh - NHEADS : bh;
      int w  = (2 << h) - 1;
      int len = min(i + 1, w);
      float inv = 1.0f / (float)len;
      int lo = i - w + 1;
      f32x4 r;
      r.x = (j0     <= i && j0     >= lo) ? inv : 0.f;
      r.y = (j0 + 1 <= i && j0 + 1 >= lo) ? inv : 0.f;
      r.z = (j0 + 2 <= i && j0 + 2 >= lo) ? inv : 0.f;
      r.w = (j0 + 3 <= i && j0 + 3 >= lo) ? inv : 0.f;
      __builtin_nontemporal_store(r, &aw[t]);      // bypass L2: protect W-matrix reuse
    }
    return;
  }

  // ---- GEMM path ----
  __shared__ __align__(16) u16 As[128 * 32];   // row-major, row stride 32 bf16 (64 B)
  __shared__ __align__(16) u16 Bs[128 * 32];
  __shared__ float colpart[4][128];            // 32-row-group column sums

  const int tid  = threadIdx.x;
  const int wave = tid >> 6;
  const int lane = tid & 63;
  const int l15  = lane & 15;
  const int quad = lane >> 4;
  const int bm = (blockIdx.x / (DMODEL / 128)) * 128;
  const int bn = (blockIdx.x % (DMODEL / 128)) * 128;
  const int wm = (wave >> 1) * 64;
  const int wn = (wave & 1) * 64;

  f32x4 acc[4][4] = {};

  const int srow = wave * 32 + (lane >> 2);
  const int skk  = (lane & 3) * 8;
  const u16* gA = A + (size_t)(bm + srow) * Kdim + skk;
  const u16* gB = B + (size_t)(bn + srow) * Kdim + skk;
  u16* lA = &As[(wave * 32) * 32];
  u16* lB = &Bs[(wave * 32) * 32];
  const size_t rstep16 = (size_t)16 * Kdim;

  for (int k0 = 0; k0 < Kdim; k0 += 32) {
    gld_lds16(lA,           gA + k0);
    gld_lds16(lA + 16 * 32, gA + k0 + rstep16);
    gld_lds16(lB,           gB + k0);
    gld_lds16(lB + 16 * 32, gB + k0 + rstep16);
    __syncthreads();

    bf16x8 af[4], bfr[4];
#pragma unroll
    for (int i = 0; i < 4; ++i)
      af[i] = *(const bf16x8*)&As[(wm + i * 16 + l15) * 32 + quad * 8];
#pragma unroll
    for (int j = 0; j < 4; ++j)
      bfr[j] = *(const bf16x8*)&Bs[(wn + j * 16 + l15) * 32 + quad * 8];
#pragma unroll
    for (int i = 0; i < 4; ++i)
#pragma unroll
      for (int j = 0; j < 4; ++j)
        acc[i][j] = __builtin_amdgcn_mfma_f32_16x16x32_bf16(af[i], bfr[j], acc[i][j], 0, 0, 0);
    __syncthreads();
  }

  // epilogue: C/D layout col = lane&15, row = quad*4 + reg   [verified m89/m91]
  const int r0 = quad * 4;
#pragma unroll
  for (int j = 0; j < 4; ++j) {
    const int col = bn + wn + j * 16 + l15;
    const float bj = bias[col];
    float sA = 0.f, sB = 0.f;     // rows [wm, wm+32) and [wm+32, wm+64)
#pragma unroll
    for (int i = 0; i < 4; ++i) {
      const int row = bm + wm + i * 16 + r0;
#pragma unroll
      for (int r = 0; r < 4; ++r) {
        float cv = acc[i][j][r] + bj;
        if constexpr (sizeof(CT) == 2)
          C[(size_t)(row + r) * Ndim + col] = (CT)f2bf(cv);
        else
          C[(size_t)(row + r) * Ndim + col] = (CT)cv;
        if (WITH_CSUM) { if (i < 2) sA += cv; else sB += cv; }
      }
    }
    if (WITH_CSUM) {
      sA += __shfl_xor(sA, 16); sA += __shfl_xor(sA, 32);
      sB += __shfl_xor(sB, 16); sB += __shfl_xor(sB, 32);
      if (quad == 0) {
        colpart[(wm >> 5) | 0][wn + j * 16 + l15] = sA;
        colpart[(wm >> 5) | 1][wn + j * 16 + l15] = sB;
      }
    }
  }
  if (WITH_CSUM) {
    __syncthreads();
    if (tid < 128) {
      const int b  = bm >> 11;               // 2048 rows per batch
      const int c0 = (bm & 2047) >> 5;       // first 32-row chunk of this tile
#pragma unroll
      for (int g = 0; g < 4; ++g)
        cs[((size_t)b * NCHUNK + c0 + g) * DMODEL + bn + tid] = colpart[g][tid];
    }
  }
}

// ---------------------------------------------------------------- exclusive chunk prefix
// E[b,c,d] = sum_{cc<c} cs[b,cc,d] = P[c*32 - 1].  One thread per (b,c,d);
// <=63 INDEPENDENT L2-resident loads (no dependent chain), fully coalesced.
__global__ void chunk_prefix(const float* __restrict__ cs, float* __restrict__ E) {
  int t = blockIdx.x * blockDim.x + threadIdx.x;   // NBATCH*NCHUNK*DMODEL = 196608
  int d = t % DMODEL;
  int c = (t / DMODEL) % NCHUNK;
  int b = t / (DMODEL * NCHUNK);
  const float* p = cs + (size_t)b * NCHUNK * DMODEL + d;
  float s = 0.f;
  for (int cc = 0; cc < c; ++cc) s += p[(size_t)cc * DMODEL];   // block-uniform trip
  E[t] = s;
}

// ---------------------------------------------------------------- windowed average (strip=8)
// One thread per (b, 8-row strip, d): 786k threads / 3072 blocks, ~45 bf16
// loads per strip against L3-resident v16. Branches wave-uniform (64
// consecutive d never cross a head boundary).
__global__ void winavg_strip(const u16* __restrict__ v, const float* __restrict__ E,
                             u16* __restrict__ A2) {
  int t = blockIdx.x * blockDim.x + threadIdx.x;   // NBATCH*(S_LEN/8)*DMODEL = 786432
  int d = t % DMODEL;
  int s = (t / DMODEL) & 255;                      // strip index, S_LEN/8 = 256
  int b = t / (DMODEL * 256);
  const int h = d >> 7;
  const int w = (2 << h) - 1;                      // 2^(h+1)-1
  const u16* vb  = v + (size_t)b * S_LEN * DMODEL + d;
  const float* Eb = E + (size_t)b * NCHUNK * DMODEL + d;

  const int i0 = s * 8;
  // lead = P[i0-1]
  float lead = Eb[(size_t)(i0 >> 5) * DMODEL];
  for (int r = i0 & ~31; r < i0; ++r)              // trip in {0,8,16,24}, uniform
    lead += bf2f(vb[(size_t)r * DMODEL]);

  // trail = P[jf-1] where jf = first trail index the strip will consume
  float trail = 0.f;
  if (i0 + 7 >= w) {                               // wave-uniform
    const int jf = max(i0, w) - w;
    if (jf > 0) {
      const int ct = (jf - 1) >> 5;
      trail = Eb[(size_t)ct * DMODEL];
      for (int r = ct * 32; r < jf; ++r)           // trip <=32, uniform
        trail += bf2f(vb[(size_t)r * DMODEL]);
    }
  }

  u16* out = A2 + ((size_t)(b * S_LEN + i0)) * DMODEL + d;
#pragma unroll
  for (int rr = 0; rr < 8; ++rr) {
    const int i = i0 + rr;
    lead += bf2f(vb[(size_t)i * DMODEL]);          // lead = P[i]
    float o;
    if (i < w) {                                   // window not yet full (uniform)
      o = lead / (float)(i + 1);
    } else {
      trail += bf2f(vb[(size_t)(i - w) * DMODEL]); // trail = P[i-w]
      o = (lead - trail) / (float)w;
    }
    out[(size_t)rr * DMODEL] = f2bf(o);
  }
}

// ---------------------------------------------------------------- launch
extern "C" void kernel_launch(void* const* d_in, const int* in_sizes, int n_in,
                              void* d_out, int out_size, void* d_ws, size_t ws_size,
                              hipStream_t stream) {
  const float* hidden = (const float*)d_in[0];
  const float* W_fc   = (const float*)d_in[1];
  const float* b_fc   = (const float*)d_in[2];
  const float* W_proj = (const float*)d_in[3];
  const float* b_proj = (const float*)d_in[4];
  float* outp = (float*)d_out;
  f32x4* aw = (f32x4*)(outp + (size_t)MROWS * DMODEL);

  // workspace layout (bytes), total 36.2 MB:
  //   0        : A16   (12,582,912)  hidden bf16, later reused as winavg-output bf16
  //   12582912 : Wfc16 ( 4,718,592)
  //   17301504 : Wpj16 ( 4,718,592)
  //   22020096 : v16   (12,582,912)  bf16 v from GEMM1
  //   34603008 : csums (   786,432)  [B, NCHUNK, D] fp32 32-row chunk sums
  //   35389440 : Epre  (   786,432)  [B, NCHUNK, D] fp32 exclusive chunk prefix
  char* ws = (char*)d_ws;
  u16*   A16   = (u16*)(ws);
  u16*   Wfc16 = (u16*)(ws + 12582912);
  u16*   Wpj16 = (u16*)(ws + 17301504);
  u16*   v16   = (u16*)(ws + 22020096);
  float* csums = (float*)(ws + 34603008);
  float* Epre  = (float*)(ws + 35389440);

  // 1) all fp32->bf16 conversions in one launch
  cvt_all<<<10752, 256, 0, stream>>>((const float4*)hidden, (const float4*)W_fc,
                                     (const float4*)W_proj, (ushort4*)A16,
                                     (ushort4*)Wfc16, (ushort4*)Wpj16);

  // 2) GEMM1 (v = hidden @ W_fc^T + b_fc -> bf16, fused chunk sums)
  //    + first half of attn_weights hidden under the MFMA time
  gemm_aw<true, u16><<<NGEMM_BLK + AW_BLK, 256, 0, stream>>>(
      A16, Wfc16, b_fc, v16, csums, aw, 0u, AW_HALF4, DMODEL, DMODEL);

  // 3a) exclusive prefix of chunk sums (tiny, parallel)
  chunk_prefix<<<(NBATCH * NCHUNK * DMODEL) / 256, 256, 0, stream>>>(csums, Epre);

  // 3b) windowed average, 8-row strips, fully parallel -> bf16 (reuse A16)
  winavg_strip<<<(NBATCH * (S_LEN / 8) * DMODEL) / 256, 256, 0, stream>>>(v16, Epre, A16);

  // 4) GEMM2 (out = winavg @ W_proj^T + b_proj -> d_out fp32)
  //    + second half of attn_weights
  gemm_aw<false, float><<<NGEMM_BLK + AW_BLK, 256, 0, stream>>>(
      A16, Wpj16, b_proj, outp, nullptr, aw, AW_HALF4, AW_HALF4, DMODEL, DMODEL);
}